// Round 4
// baseline (313.126 us; speedup 1.0000x reference)
//
#include <hip/hip_runtime.h>

// Shapes: B=4, S=2048, D=256, H=8, KD=256; N=B*S=8192; H*KD=2048.
using bf16x8 = __attribute__((ext_vector_type(8))) __bf16;
using f32x4  = __attribute__((ext_vector_type(4))) float;
using f32x16 = __attribute__((ext_vector_type(16))) float;
typedef unsigned short u16;
typedef const __attribute__((address_space(1))) void* gas_p;
typedef __attribute__((address_space(3))) void* las_p;

__device__ __forceinline__ u16 f2bf(float f) {
  union { float f; unsigned u; } v; v.f = f;
  unsigned r = v.u + 0x7fffu + ((v.u >> 16) & 1u);
  return (u16)(r >> 16);
}

__device__ __forceinline__ unsigned pkbf(float a, float b) {
  unsigned r;
  asm("v_cvt_pk_bf16_f32 %0, %1, %2" : "=v"(r) : "v"(a), "v"(b));
  return r;
}

__device__ __forceinline__ void gload16(const void* g, void* l) {
  __builtin_amdgcn_global_load_lds((gas_p)g, (las_p)l, 16, 0, 0);
}

#define MFMA(a, b, c)   __builtin_amdgcn_mfma_f32_16x16x32_bf16((a), (b), (c), 0, 0, 0)
#define MFMA32(a, b, c) __builtin_amdgcn_mfma_f32_32x32x16_bf16((a), (b), (c), 0, 0, 0)

// ---------------------------------------------------------------------------
// Kernel 1: transpose + f32->bf16 convert for the 4 weight matrices.
__global__ __launch_bounds__(256) void transpose_conv(
    const float* __restrict__ Wq, const float* __restrict__ Wk,
    const float* __restrict__ Wv, const float* __restrict__ Wo,
    u16* __restrict__ wqt, u16* __restrict__ wkt,
    u16* __restrict__ wvt, u16* __restrict__ wot)
{
  int z = blockIdx.y;
  const float* src = (z == 0) ? Wq : (z == 1) ? Wk : (z == 2) ? Wv : Wo;
  u16* dst = (z == 0) ? wqt : (z == 1) ? wkt : (z == 2) ? wvt : wot;
  int C = (z < 3) ? 2048 : 256;   // src cols
  int R = (z < 3) ? 256 : 2048;   // src rows
  int TC = C >> 5;
  int tc = blockIdx.x % TC, tr = blockIdx.x / TC;
  __shared__ float tile[32][33];
  int j = threadIdx.x & 31, i0 = threadIdx.x >> 5;
#pragma unroll
  for (int p = 0; p < 4; p++)
    tile[i0 + p * 8][j] = src[(tr * 32 + i0 + p * 8) * C + tc * 32 + j];
  __syncthreads();
#pragma unroll
  for (int p = 0; p < 4; p++)
    dst[(tc * 32 + i0 + p * 8) * R + tr * 32 + j] = f2bf(tile[j][i0 + p * 8]);
}

// ---------------------------------------------------------------------------
// Kernel 2: LayerNorm for the 3 input streams, f32 -> bf16. One wave per row.
__global__ __launch_bounds__(256) void ln3_kernel(
    const float* __restrict__ xq, const float* __restrict__ xk, const float* __restrict__ xv,
    const float* __restrict__ gq, const float* __restrict__ bq,
    const float* __restrict__ gk, const float* __restrict__ bk,
    const float* __restrict__ gv, const float* __restrict__ bv,
    u16* __restrict__ oq, u16* __restrict__ ok, u16* __restrict__ ov)
{
  int z = blockIdx.y;
  const float* x = (z == 0) ? xq : (z == 1) ? xk : xv;
  const float* g = (z == 0) ? gq : (z == 1) ? gk : gv;
  const float* be = (z == 0) ? bq : (z == 1) ? bk : bv;
  u16* o = (z == 0) ? oq : (z == 1) ? ok : ov;
  int w = threadIdx.x >> 6, l = threadIdx.x & 63;
  int row = blockIdx.x * 4 + w;
  float4 x4 = *(const float4*)(x + row * 256 + l * 4);
  float s = x4.x + x4.y + x4.z + x4.w;
  float sq = x4.x * x4.x + x4.y * x4.y + x4.z * x4.z + x4.w * x4.w;
#pragma unroll
  for (int mm = 1; mm < 64; mm <<= 1) { s += __shfl_xor(s, mm); sq += __shfl_xor(sq, mm); }
  float mu = s * (1.f / 256.f);
  float var = sq * (1.f / 256.f) - mu * mu;
  float rs = rsqrtf(var + 1e-5f);
  float4 g4 = *(const float4*)(g + l * 4);
  float4 b4 = *(const float4*)(be + l * 4);
  ushort4 o4;
  o4.x = f2bf((x4.x - mu) * rs * g4.x + b4.x);
  o4.y = f2bf((x4.y - mu) * rs * g4.y + b4.y);
  o4.z = f2bf((x4.z - mu) * rs * g4.z + b4.z);
  o4.w = f2bf((x4.w - mu) * rs * g4.w + b4.w);
  *(ushort4*)(o + row * 256 + l * 4) = o4;
}

// ---------------------------------------------------------------------------
// Kernel 3: projection GEMM. C[8192][2048] = A[8192][256] * W[256][2048] (+bias)
// z==2 (V stream) writes V^T [32 bh][256 kd][2048 s] directly (fused transpose).
__global__ __launch_bounds__(256) void proj_gemm(
    const u16* __restrict__ qn, const u16* __restrict__ kn, const u16* __restrict__ vn,
    const u16* __restrict__ wqt, const u16* __restrict__ wkt, const u16* __restrict__ wvt,
    const float* __restrict__ bq, const float* __restrict__ bk, const float* __restrict__ bv,
    u16* __restrict__ qo, u16* __restrict__ ko, u16* __restrict__ vo)
{
  __shared__ u16 As[128 * 64];
  __shared__ u16 Bs[128 * 64];
  int z = blockIdx.z;
  const u16* A  = (z == 0) ? qn : (z == 1) ? kn : vn;
  const u16* Bt = (z == 0) ? wqt : (z == 1) ? wkt : wvt;
  const float* bias = (z == 0) ? bq : (z == 1) ? bk : bv;
  u16* Co = (z == 0) ? qo : (z == 1) ? ko : vo;
  float scale = (z == 0) ? 0.0625f : 1.0f;

  int i0 = blockIdx.x * 128, n0 = blockIdx.y * 128;
  int tid = threadIdx.x, w = tid >> 6, l = tid & 63;
  int wr = w >> 1, wc = w & 1, l15 = l & 15, qv = l >> 4;

  f32x4 acc[4][4] = {};

  for (int k0 = 0; k0 < 256; k0 += 64) {
    __syncthreads();
#pragma unroll
    for (int j = 0; j < 4; j++) {
      int c = (w * 4 + j) * 64 + l;
      int row = c >> 3, co = (c & 7) * 8;
      gload16(A + (i0 + row) * 256 + k0 + co, (char*)As + (w * 4 + j) * 1024);
      gload16(Bt + (n0 + row) * 256 + k0 + co, (char*)Bs + (w * 4 + j) * 1024);
    }
    __syncthreads();
#pragma unroll
    for (int kk = 0; kk < 2; kk++) {
      bf16x8 a[4], bfr[4];
#pragma unroll
      for (int m = 0; m < 4; m++)
        a[m] = *(const bf16x8*)(As + (wr * 64 + m * 16 + l15) * 64 + kk * 32 + qv * 8);
#pragma unroll
      for (int n = 0; n < 4; n++)
        bfr[n] = *(const bf16x8*)(Bs + (wc * 64 + n * 16 + l15) * 64 + kk * 32 + qv * 8);
#pragma unroll
      for (int m = 0; m < 4; m++)
#pragma unroll
        for (int n = 0; n < 4; n++) acc[m][n] = MFMA(a[m], bfr[n], acc[m][n]);
    }
  }

  if (z == 2) {
    // V^T epilogue: vt[(bb*8+h)*256 + kd][ss..ss+3], 8B packed stores.
#pragma unroll
    for (int n = 0; n < 4; n++) {
      int col = n0 + wc * 64 + n * 16 + l15;
      float bc = bias[col];
      int h = col >> 8, kd = col & 255;
#pragma unroll
      for (int m = 0; m < 4; m++) {
        int row0 = i0 + wr * 64 + m * 16 + qv * 4;
        int bb = row0 >> 11, ss = row0 & 2047;
        ushort4 o4;
        o4.x = f2bf(acc[m][n][0] + bc);
        o4.y = f2bf(acc[m][n][1] + bc);
        o4.z = f2bf(acc[m][n][2] + bc);
        o4.w = f2bf(acc[m][n][3] + bc);
        *(ushort4*)(Co + ((size_t)(bb * 8 + h) * 256 + kd) * 2048 + ss) = o4;
      }
    }
  } else {
#pragma unroll
    for (int n = 0; n < 4; n++) {
      int col = n0 + wc * 64 + n * 16 + l15;
      float bc = bias[col];
      int h = col >> 8, kd = col & 255;
#pragma unroll
      for (int m = 0; m < 4; m++) {
#pragma unroll
        for (int r = 0; r < 4; r++) {
          int row = i0 + wr * 64 + m * 16 + qv * 4 + r;
          int bb = row >> 11, ss = row & 2047;
          Co[((bb * 8 + h) * 2048 + ss) * 256 + kd] = f2bf((acc[m][n][r] + bc) * scale);
        }
      }
    }
  }
}

// ---------------------------------------------------------------------------
// Kernel 5: flash attention, 32x32x16 MFMA, swapped operands.
// 4 waves x 32 q = 128 q/block; KVBLK=32; double-buffered 2x32KB LDS ->
// 2 blocks/CU (two independent barrier domains anti-phase on one CU).
// Grid 512 flat; XCD swizzle: xcd=f&7, bh=xcd*4+(slot&3), qt=slot>>2.
// K tile [32 s][512B] 5-bit XOR swizzle; V^T tile [64 rows][256B] (4 d/row),
// 4-bit XOR swizzle. QK^T: S^T=mfma(K,Q) -> lane owns q=l31; PV: O^T=mfma(V,P).
__global__ __launch_bounds__(256, 2) void flash_attn(
    const u16* __restrict__ q, const u16* __restrict__ k,
    const u16* __restrict__ vt, u16* __restrict__ o)
{
  __shared__ char lds[65536];
  int f = blockIdx.x;
  int slot = f >> 3;
  int bh = (f & 7) * 4 + (slot & 3);
  int qt = slot >> 2;
  int b = bh >> 3, hh = bh & 7;
  int tid = threadIdx.x, w = tid >> 6, l = tid & 63;
  int l31 = l & 31, h = l >> 5;

  const u16* Q = q + (size_t)(bh * 2048 + qt * 128 + w * 32) * 256;
  const u16* K = k + (size_t)bh * 2048 * 256;
  const u16* V = vt + (size_t)bh * 256 * 2048;   // V^T [256][2048]

  // Q B-fragments: lane holds q-row = l31, d-slice = dt*16 + h*8 .. +8.
  bf16x8 qf[16];
#pragma unroll
  for (int dt = 0; dt < 16; dt++)
    qf[dt] = *(const bf16x8*)(Q + l31 * 256 + dt * 16 + h * 8);

  f32x16 oacc[8] = {};
  float m_ = -1e30f, lsum = 0.f;

  // Stage K/V tile t (32 s) into base: K 16KB [32 rows x 512B, slot^row],
  // V 16KB [64 rows x 256B, granule^(row&15)]. 4 waves x 8 gload16.
  auto stage = [&](int t, char* base) {
#pragma unroll
    for (int j = 0; j < 4; j++) {
      int c = w * 4 + j;
      int off = c * 1024 + l * 16;
      {
        int r = off >> 9, ps = (off >> 4) & 31;
        gload16(K + (size_t)(t * 32 + r) * 256 + ((ps ^ r) << 3), base + off);
      }
      {
        int r = off >> 8, g = (off >> 4) & 15;
        int gg = g ^ (r & 15);
        int d = r * 4 + (gg >> 2), s0 = (gg & 3) * 8;
        gload16(V + (size_t)d * 2048 + t * 32 + s0, base + 16384 + off);
      }
    }
  };

  stage(0, lds);
  __syncthreads();

  for (int t = 0; t < 64; t++) {
    char* cur = lds + (size_t)(t & 1) * 32768;
    char* nxt = lds + (size_t)((t + 1) & 1) * 32768;
    if (t + 1 < 64) stage(t + 1, nxt);   // async DMA into other buffer

    // ---- QK^T: p = S^T tile [32 s][32 q], lane col q = l31.
    f32x16 p = {};
    __builtin_amdgcn_s_setprio(1);
#pragma unroll
    for (int dt = 0; dt < 16; dt++) {
      bf16x8 kf = *(const bf16x8*)(cur + l31 * 512 + (((dt * 2 + h) ^ l31) << 4));
      p = MFMA32(kf, qf[dt], p);
    }
    __builtin_amdgcn_s_setprio(0);

    // ---- online softmax (lane-local; q = l31 on both halves).
    float n0 = fmaxf(fmaxf(p[0], p[1]), fmaxf(p[2], p[3]));
    float n1 = fmaxf(fmaxf(p[4], p[5]), fmaxf(p[6], p[7]));
    float n2 = fmaxf(fmaxf(p[8], p[9]), fmaxf(p[10], p[11]));
    float n3 = fmaxf(fmaxf(p[12], p[13]), fmaxf(p[14], p[15]));
    float mt = fmaxf(fmaxf(n0, n1), fmaxf(n2, n3));
    mt = fmaxf(mt, __shfl_xor(mt, 32));
    if (__any(mt > m_ + 8.0f)) {               // defer-max (T13)
      float mn = fmaxf(m_, mt);
      float fsc = __expf(m_ - mn);
      lsum *= fsc;
#pragma unroll
      for (int dt = 0; dt < 8; dt++)
#pragma unroll
        for (int i = 0; i < 16; i++) oacc[dt][i] *= fsc;
      m_ = mn;
    }
#pragma unroll
    for (int i = 0; i < 16; i++) { p[i] = __expf(p[i] - m_); lsum += p[i]; }

    // ---- pack P to bf16 pairs.
    unsigned pw[8];
#pragma unroll
    for (int i = 0; i < 8; i++) pw[i] = pkbf(p[2 * i], p[2 * i + 1]);

    // ---- PV: per k-tile build P^T B-frag (cross-half exchange), 8 d-tiles.
#pragma unroll
    for (int kt = 0; kt < 2; kt++) {
      unsigned x0 = __shfl_xor(pw[4 * kt + 0], 32);
      unsigned x1 = __shfl_xor(pw[4 * kt + 1], 32);
      unsigned x2 = __shfl_xor(pw[4 * kt + 2], 32);
      unsigned x3 = __shfl_xor(pw[4 * kt + 3], 32);
      union { unsigned u[4]; bf16x8 v; } pa;
      pa.u[0] = h ? x2 : pw[4 * kt + 0];
      pa.u[1] = h ? x3 : pw[4 * kt + 1];
      pa.u[2] = h ? pw[4 * kt + 2] : x0;
      pa.u[3] = h ? pw[4 * kt + 3] : x1;
      __builtin_amdgcn_s_setprio(1);
#pragma unroll
      for (int dt = 0; dt < 8; dt++) {
        int d = dt * 32 + l31;
        int r = d >> 2;
        int gg = (d & 3) * 4 + kt * 2 + h;
        bf16x8 vf = *(const bf16x8*)(cur + 16384 + r * 256 + ((gg ^ (r & 15)) << 4));
        oacc[dt] = MFMA32(vf, pa.v, oacc[dt]);
      }
      __builtin_amdgcn_s_setprio(0);
    }

    asm volatile("s_waitcnt vmcnt(0)" ::: "memory");
    __syncthreads();
  }

  // ---- epilogue: normalize (lane-local q), transpose via LDS, store 16B.
  float inv = 1.0f / (lsum + __shfl_xor(lsum, 32));
  char* wbase = (char*)lds + w * 8192;   // 16 q-rows x 512B per wave region
  int qr15 = l31 & 15;
#pragma unroll
  for (int ph = 0; ph < 2; ph++) {
    if ((l31 >> 4) == ph) {
#pragma unroll
      for (int dt = 0; dt < 8; dt++) {
#pragma unroll
        for (int rg = 0; rg < 4; rg++) {
          uint2 uu;
          uu.x = pkbf(oacc[dt][rg * 4 + 0] * inv, oacc[dt][rg * 4 + 1] * inv);
          uu.y = pkbf(oacc[dt][rg * 4 + 2] * inv, oacc[dt][rg * 4 + 3] * inv);
          *(uint2*)(wbase + qr15 * 512 + ((dt * 64 + rg * 16) ^ (qr15 << 4)) + h * 8) = uu;
        }
      }
    }
    asm volatile("s_waitcnt lgkmcnt(0)" ::: "memory");
    __builtin_amdgcn_sched_barrier(0);
#pragma unroll
    for (int c = 0; c < 8; c++) {
      int qr = c * 2 + h;
      uint4 vv = *(const uint4*)(wbase + qr * 512 + ((l31 ^ qr) << 4));
      int s = qt * 128 + w * 32 + ph * 16 + qr;
      *(uint4*)((char*)o + (size_t)(b * 2048 + s) * 4096 + hh * 512 + l31 * 16) = vv;
    }
    asm volatile("s_waitcnt lgkmcnt(0)" ::: "memory");
  }
}

// ---------------------------------------------------------------------------
// Kernel 6: output projection + bias + residual.
__global__ __launch_bounds__(256) void out_gemm(
    const u16* __restrict__ A, const u16* __restrict__ Bt,
    const float* __restrict__ bo, const float* __restrict__ resid,
    float* __restrict__ out)
{
  __shared__ u16 As[128 * 64];
  __shared__ u16 Bs[64 * 64];
  int i0 = blockIdx.x * 128, n0 = blockIdx.y * 64;
  int tid = threadIdx.x, w = tid >> 6, l = tid & 63, l15 = l & 15, qv = l >> 4;

  f32x4 acc[2][4] = {};

  for (int k0 = 0; k0 < 2048; k0 += 64) {
    __syncthreads();
#pragma unroll
    for (int j = 0; j < 4; j++) {
      int c = (w * 4 + j) * 64 + l;
      int row = c >> 3, co = (c & 7) * 8;
      gload16(A + (i0 + row) * 2048 + k0 + co, (char*)As + (w * 4 + j) * 1024);
    }
#pragma unroll
    for (int j = 0; j < 2; j++) {
      int c = (w * 2 + j) * 64 + l;
      int row = c >> 3, co = (c & 7) * 8;
      gload16(Bt + (n0 + row) * 2048 + k0 + co, (char*)Bs + (w * 2 + j) * 1024);
    }
    __syncthreads();
#pragma unroll
    for (int kk = 0; kk < 2; kk++) {
      bf16x8 a[2], bfr[4];
#pragma unroll
      for (int m = 0; m < 2; m++)
        a[m] = *(const bf16x8*)(As + (w * 32 + m * 16 + l15) * 64 + kk * 32 + qv * 8);
#pragma unroll
      for (int n = 0; n < 4; n++)
        bfr[n] = *(const bf16x8*)(Bs + (n * 16 + l15) * 64 + kk * 32 + qv * 8);
#pragma unroll
      for (int m = 0; m < 2; m++)
#pragma unroll
        for (int n = 0; n < 4; n++) acc[m][n] = MFMA(a[m], bfr[n], acc[m][n]);
    }
  }

#pragma unroll
  for (int n = 0; n < 4; n++) {
    int col = n0 + n * 16 + l15;
    float bc = bo[col];
#pragma unroll
    for (int m = 0; m < 2; m++)
#pragma unroll
      for (int r = 0; r < 4; r++) {
        int row = i0 + w * 32 + m * 16 + qv * 4 + r;
        out[row * 256 + col] = acc[m][n][r] + bc + resid[row * 256 + col];
      }
  }
}

// ---------------------------------------------------------------------------
extern "C" void kernel_launch(void* const* d_in, const int* in_sizes, int n_in,
                              void* d_out, int out_size, void* d_ws, size_t ws_size,
                              hipStream_t stream)
{
  const float* inq  = (const float*)d_in[0];
  const float* key  = (const float*)d_in[1];
  const float* val  = (const float*)d_in[2];
  const float* gq   = (const float*)d_in[3];
  const float* bqln = (const float*)d_in[4];
  const float* gk   = (const float*)d_in[5];
  const float* bkln = (const float*)d_in[6];
  const float* gv   = (const float*)d_in[7];
  const float* bvln = (const float*)d_in[8];
  const float* Wq   = (const float*)d_in[9];
  const float* bq   = (const float*)d_in[10];
  const float* Wk   = (const float*)d_in[11];
  const float* bk   = (const float*)d_in[12];
  const float* Wv   = (const float*)d_in[13];
  const float* bv   = (const float*)d_in[14];
  const float* Wo   = (const float*)d_in[15];
  const float* bo   = (const float*)d_in[16];

  char* ws = (char*)d_ws;
  const size_t MB = 1ull << 20;
  u16* wqt = (u16*)(ws + 0 * MB);    // [2048][256] bf16
  u16* wkt = (u16*)(ws + 1 * MB);
  u16* wvt = (u16*)(ws + 2 * MB);
  u16* wot = (u16*)(ws + 3 * MB);    // [256][2048] bf16
  u16* qn  = (u16*)(ws + 4 * MB);    // [8192][256] bf16
  u16* kn  = (u16*)(ws + 8 * MB);
  u16* vn  = (u16*)(ws + 12 * MB);
  u16* qws = (u16*)(ws + 16 * MB);   // [32][2048][256] bf16 (q, pre-scaled 1/16)
  u16* kws = (u16*)(ws + 48 * MB);   // [32][2048][256] bf16
  u16* attn = (u16*)(ws + 80 * MB);  // [8192][2048] bf16 (attention output)
  u16* vtw = (u16*)(ws + 112 * MB);  // [32][256][2048] bf16 (V^T, written by proj)

  transpose_conv<<<dim3(512, 4), 256, 0, stream>>>(Wq, Wk, Wv, Wo, wqt, wkt, wvt, wot);
  ln3_kernel<<<dim3(2048, 3), 256, 0, stream>>>(inq, key, val, gq, bqln, gk, bkln, gv, bvln,
                                                qn, kn, vn);
  proj_gemm<<<dim3(64, 16, 3), 256, 0, stream>>>(qn, kn, vn, wqt, wkt, wvt, bq, bk, bv,
                                                 qws, kws, vtw);
  flash_attn<<<512, 256, 0, stream>>>(qws, kws, vtw, attn);
  out_gemm<<<dim3(64, 4), 256, 0, stream>>>(attn, wot, bo, inq, (float*)d_out);
}